// Round 15
// baseline (293.070 us; speedup 1.0000x reference)
//
#include <hip/hip_runtime.h>
#include <hip/hip_bf16.h>

// Problem constants
#define TSEG 8
#define NBC 4          // clips
#define NBT 32         // B*T
#define CIN 256
#define CH 64
#define HIN 112
#define WIN_ 112
#define HO 56
#define WO 56
#define HPD 64
#define WPD 64

#define FRSZE ((size_t)(HPD * WPD * CH))    // 262144 bf16 elems per padded frame
#define ZF_U   147456
#define FR_U   (ZF_U + 262144)               // ushort offset of the 32 real frames
#define WS_TOTAL_BYTES ((size_t)(FR_U + 32 * 262144) * 2)   // 17,596,416 B

typedef __attribute__((ext_vector_type(8))) short bf16x8;
typedef __attribute__((ext_vector_type(4))) float f32x4;

// hardware RNE f32->bf16 (compiler fuses adjacent pairs to v_cvt_pk_bf16_f32)
__device__ __forceinline__ unsigned short f2bf(float f) {
    __hip_bfloat16 h = __float2bfloat16(f);
    union { __hip_bfloat16 h; unsigned short u; } c; c.h = h;
    return c.u;
}
__device__ __forceinline__ unsigned pk2bf(float lo, float hi) {
    return (unsigned)f2bf(lo) | ((unsigned)f2bf(hi) << 16);
}

// ---------------------------------------------------------------------------
// Weight prep: w[cout][ci][kh][kw] fp32 -> w''[tap][cout][ci] bf16 (RNE)
// ---------------------------------------------------------------------------
__global__ __launch_bounds__(256) void wprep_k(
    const float* __restrict__ w, unsigned short* __restrict__ wpp)
{
    int e = blockIdx.x * 256 + threadIdx.x;     // < 147456
    int cout = e / 2304;
    int rem  = e - cout * 2304;
    int ci   = rem / 9;
    int tap  = rem - ci * 9;
    wpp[((size_t)tap * 64 + cout) * 256 + ci] = f2bf(w[e]);
}

// ---------------------------------------------------------------------------
// Conv3x3 s2 p1 + BN + ReLU + per-pixel L2 norm, via bf16 MFMA implicit GEMM.
// (unchanged from R13/R14 — parked at ~118 us)
// ---------------------------------------------------------------------------
__global__ __launch_bounds__(256) void conv_mfma_k(
    const float* __restrict__ x, const unsigned short* __restrict__ wpp,
    const float* __restrict__ gamma, const float* __restrict__ beta,
    const float* __restrict__ mean, const float* __restrict__ var,
    unsigned short* __restrict__ frames)
{
    __shared__ unsigned short in_lds[5 * 120 * 32];   // 38,400 B, swizzled
    __shared__ float sq[2][2][64];

    const int tid  = threadIdx.x;
    const int lane = tid & 63;
    const int wv   = tid >> 6;
    const int r    = wv >> 1;
    const int nh   = wv & 1;
    const int l15  = lane & 15;
    const int l4   = lane >> 4;
    const int hb   = blockIdx.x;
    const int bt   = blockIdx.y;

    const float* xb = x + (size_t)bt * (CIN * HIN * WIN_);

    f32x4 acc[4][2];
#pragma unroll
    for (int mt = 0; mt < 4; ++mt) {
        acc[mt][0] = (f32x4){0.f, 0.f, 0.f, 0.f};
        acc[mt][1] = (f32x4){0.f, 0.f, 0.f, 0.f};
    }

    int a_off[4][3];
#pragma unroll
    for (int mt = 0; mt < 4; ++mt) {
        int c = mt * 16 + l15; if (c > 55) c = 55;
#pragma unroll
        for (int kw = 0; kw < 3; ++kw) {
            int col = 2 * c + kw;
            int ba  = col * 64 + l4 * 16;
            ba ^= ((col >> 1) & 7) << 4;
            a_off[mt][kw] = ba;
        }
    }

    const unsigned short* bptr0 = wpp + ((size_t)(nh * 32 + l15) * 256 + l4 * 8);
    const unsigned short* bptr1 = wpp + ((size_t)(nh * 32 + 16 + l15) * 256 + l4 * 8);

    const int ih0 = 4 * hb - 1;

    if (tid < 20) {
        const int row = tid >> 2, cig = tid & 3;
        const int ba = (row * 120) * 64 + cig * 16;
        *(uint4*)((char*)in_lds + ba) = make_uint4(0u, 0u, 0u, 0u);
    }

    for (int cb = 0; cb < 8; ++cb) {
        __syncthreads();
        if (lane < 56) {
#pragma unroll
            for (int j = 0; j < 5; ++j) {
                const int jj  = wv + j * 4;
                const int row = jj >> 2, cig = jj & 3;
                const int ih  = ih0 + row;
                unsigned pkA[4], pkB[4];
                if (ih >= 0 && ih < HIN) {
                    const float* xr = xb + ((size_t)(cb * 32 + cig * 8) * HIN + ih) * WIN_
                                    + 2 * lane;
#pragma unroll
                    for (int q = 0; q < 4; ++q) {
                        const float2 va = *(const float2*)(xr + (size_t)(2 * q) * (HIN * WIN_));
                        const float2 vb = *(const float2*)(xr + (size_t)(2 * q + 1) * (HIN * WIN_));
                        pkA[q] = pk2bf(va.x, vb.x);
                        pkB[q] = pk2bf(va.y, vb.y);
                    }
                } else {
#pragma unroll
                    for (int q = 0; q < 4; ++q) { pkA[q] = 0u; pkB[q] = 0u; }
                }
                const int colA = 1 + 2 * lane;
                const int colB = colA + 1;
                int baA = (row * 120 + colA) * 64 + cig * 16; baA ^= ((colA >> 1) & 7) << 4;
                int baB = (row * 120 + colB) * 64 + cig * 16; baB ^= ((colB >> 1) & 7) << 4;
                *(uint4*)((char*)in_lds + baA) = make_uint4(pkA[0], pkA[1], pkA[2], pkA[3]);
                *(uint4*)((char*)in_lds + baB) = make_uint4(pkB[0], pkB[1], pkB[2], pkB[3]);
            }
        }
        __syncthreads();

        const int rowb = (2 * r) * 7680;
#pragma unroll
        for (int kh = 0; kh < 3; ++kh) {
            const int rb = rowb + kh * 7680;
#pragma unroll
            for (int kw = 0; kw < 3; ++kw) {
                const int tap = kh * 3 + kw;
                const bf16x8 bf0 = *(const bf16x8*)(bptr0 + tap * 16384 + cb * 32);
                const bf16x8 bf1 = *(const bf16x8*)(bptr1 + tap * 16384 + cb * 32);
#pragma unroll
                for (int mt = 0; mt < 4; ++mt) {
                    const bf16x8 af = *(const bf16x8*)((const char*)in_lds + (rb + a_off[mt][kw]));
                    acc[mt][0] = __builtin_amdgcn_mfma_f32_16x16x32_bf16(af, bf0, acc[mt][0], 0, 0, 0);
                    acc[mt][1] = __builtin_amdgcn_mfma_f32_16x16x32_bf16(af, bf1, acc[mt][1], 0, 0, 0);
                }
            }
        }
    }

    const int cout0 = nh * 32 + l15;
    const int cout1 = cout0 + 16;
    const float sc0 = gamma[cout0] * rsqrtf(var[cout0] + 1e-5f);
    const float bb0 = beta[cout0] - mean[cout0] * sc0;
    const float sc1 = gamma[cout1] * rsqrtf(var[cout1] + 1e-5f);
    const float bb1 = beta[cout1] - mean[cout1] * sc1;

    float yv[4][2][4];
    float ssr[4][4];
#pragma unroll
    for (int mt = 0; mt < 4; ++mt) {
#pragma unroll
        for (int reg = 0; reg < 4; ++reg) {
            float y0 = fmaxf(fmaf(acc[mt][0][reg], sc0, bb0), 0.f);
            float y1 = fmaxf(fmaf(acc[mt][1][reg], sc1, bb1), 0.f);
            yv[mt][0][reg] = y0; yv[mt][1][reg] = y1;
            float ss = y0 * y0 + y1 * y1;
            ss += __shfl_xor(ss, 1);
            ss += __shfl_xor(ss, 2);
            ss += __shfl_xor(ss, 4);
            ss += __shfl_xor(ss, 8);
            ssr[mt][reg] = ss;
        }
    }
    if (l15 == 0) {
#pragma unroll
        for (int mt = 0; mt < 4; ++mt)
#pragma unroll
            for (int reg = 0; reg < 4; ++reg)
                sq[r][nh][mt * 16 + l4 * 4 + reg] = ssr[mt][reg];
    }
    __syncthreads();

    const int h = 2 * hb + r;
    unsigned short* fdst = frames + (size_t)bt * FRSZE + (size_t)(h + 4) * WPD * CH;
#pragma unroll
    for (int mt = 0; mt < 4; ++mt) {
#pragma unroll
        for (int reg = 0; reg < 4; ++reg) {
            const int c = mt * 16 + l4 * 4 + reg;
            if (c < 56) {
                const float tot = sq[r][0][c] + sq[r][1][c];
                const float inv = rsqrtf(tot + 1e-6f);
                unsigned short* dp = fdst + (size_t)(c + 4) * CH;
                dp[cout0] = f2bf(yv[mt][0][reg] * inv);
                dp[cout1] = f2bf(yv[mt][1][reg] * inv);
            }
        }
    }
}

// ---------------------------------------------------------------------------
// Pad-fill: zeros for the 6 temporal-pad (t,l) slabs.
// ---------------------------------------------------------------------------
__global__ __launch_bounds__(64) void pad_k(float* __restrict__ out)
{
    const int lane = threadIdx.x;
    const int h = blockIdx.x;
    const int p = blockIdx.y;          // 0..5
    const int b = blockIdx.z;
    const int PT[6] = {0, 0, 1, 6, 7, 7};
    const int PL[6] = {0, 1, 0, 4, 3, 4};
    const int t = PT[p], l = PL[p];
    float* ob = out + (size_t)((b * TSEG + t) * HO + h) * (WO * 405) + l * 81;
#pragma unroll 4
    for (int w = 0; w < 56; ++w) {
        float* orow = ob + (size_t)w * 405;
        orow[lane] = 0.f;
        if (lane < 17) orow[lane + 64] = 0.f;
    }
}

// ---------------------------------------------------------------------------
// Kernel 2 (R15): f-grouped correlation, balanced 5-wave blocks, direct
// register->global band stores.
// Block (b, f, h) = 320 thr (5 waves): stage the 9 Z-rows (h..h+8) of frame
// f ONCE into LDS (73.7 KB, XOR-swizzled). Wave wv computes unit l=wv,
// t=f+2-wv (invalid -> exit after barrier). Transposed MFMA C[zc][w] gives
// each lane 4 CONSECUTIVE v positions of one output row -> 28 predicated
// dword stores per u, no store-LDS (L2 absorbs scatter; R2 measured +6%).
// 2 blocks/CU -> 10 waves/CU; traffic ~390 MB (was 833).
// ---------------------------------------------------------------------------
__global__ __launch_bounds__(320) void corr_f5_k(
    const unsigned short* __restrict__ frames, float* __restrict__ out)
{
    __shared__ unsigned short zl[9 * 4096];   // 73,728 B

    const int tid  = threadIdx.x;
    const int lane = tid & 63;
    const int wv   = tid >> 6;                // 0..4
    const int l15  = lane & 15;
    const int l4   = lane >> 4;

    const int h = blockIdx.x;                 // 0..55
    const int f = blockIdx.y;                 // 0..7  (B-frame index)
    const int b = blockIdx.z;

    // ---- stage Z rows h..h+8 of frame (b,f) into swizzled LDS ----
    const unsigned short* zb = frames + (size_t)(b * TSEG + f) * FRSZE
                             + (size_t)h * (WPD * CH);
#pragma unroll
    for (int k = 0; k < 15; ++k) {
        const int e = tid + k * 320;          // < 4608
        if (e < 4608) {
            const int row = e >> 9;
            const int c   = e & 511;
            const uint4 val = *(const uint4*)(zb + (size_t)row * 4096 + c * 8);
            const int ba = row * 8192 + ((c * 16) ^ (((c >> 3) & 7) << 4));
            *(uint4*)((char*)zl + ba) = val;
        }
    }
    __syncthreads();

    const int l = wv;
    const int t = f + 2 - l;
    if (t < 0 || t > 7) return;               // edge-f waves idle
    const int bt = b * TSEG + t;

    // Z-frag read offsets (A-operand): row px = n*16+l15, k-chunk = hf*32+l4*8
    int roff[4][2];
#pragma unroll
    for (int n = 0; n < 4; ++n) {
        const int px = n * 16 + l15;
#pragma unroll
        for (int hf = 0; hf < 2; ++hf)
            roff[n][hf] = (px * 128 + hf * 64 + l4 * 16) ^ ((px & 7) << 4);
    }

    // Y fragments (B-operand): col w = m*16+l15, k = hf*32+l4*8
    const unsigned short* yb = frames + (size_t)bt * FRSZE
                             + (size_t)(h + 4) * (WPD * CH);
    bf16x8 yf[4][2];
#pragma unroll
    for (int m = 0; m < 4; ++m) {
        int wc = (m << 4) + l15; if (wc > 55) wc = 55;  // clamp, masked at store
        const unsigned short* ap = yb + (size_t)(wc + 4) * CH + (l4 << 3);
        yf[m][0] = *(const bf16x8*)(ap);
        yf[m][1] = *(const bf16x8*)(ap + 32);
    }

    float* ob = out + (size_t)(bt * HO + h) * (WO * 405) + l * 81;

    const int PM[7] = {0, 0, 1, 1, 2, 2, 3};
    const int PN[7] = {0, 1, 1, 2, 2, 3, 3};

#pragma unroll
    for (int u = 0; u < 9; ++u) {
        const char* rb = (const char*)zl + u * 8192;
        bf16x8 zf[4][2];
#pragma unroll
        for (int n = 0; n < 4; ++n) {
            zf[n][0] = *(const bf16x8*)(rb + roff[n][0]);
            zf[n][1] = *(const bf16x8*)(rb + roff[n][1]);
        }

        f32x4 acc[7];
#pragma unroll
        for (int i = 0; i < 7; ++i) acc[i] = (f32x4){0.f, 0.f, 0.f, 0.f};
#pragma unroll
        for (int i = 0; i < 7; ++i) {
            acc[i] = __builtin_amdgcn_mfma_f32_16x16x32_bf16(zf[PN[i]][0], yf[PM[i]][0], acc[i], 0, 0, 0);
            acc[i] = __builtin_amdgcn_mfma_f32_16x16x32_bf16(zf[PN[i]][1], yf[PM[i]][1], acc[i], 0, 0, 0);
        }

        // direct band store: C[zc][w], zc = PN*16+l4*4+reg, w = PM*16+l15;
        // v = zc - w consecutive across reg -> 28 predicated dword stores
#pragma unroll
        for (int i = 0; i < 7; ++i) {
            const int w = (PM[i] << 4) + l15;
            if (w < 56) {
                float* orow = ob + (size_t)w * 405 + u * 9;
                const int v0 = (PN[i] << 4) + (l4 << 2) - w;
#pragma unroll
                for (int reg = 0; reg < 4; ++reg) {
                    const int v = v0 + reg;
                    if ((unsigned)v <= 8u) orow[v] = acc[i][reg];
                }
            }
        }
    }
}

// ---------------------------------------------------------------------------
extern "C" void kernel_launch(void* const* d_in, const int* in_sizes, int n_in,
                              void* d_out, int out_size, void* d_ws, size_t ws_size,
                              hipStream_t stream)
{
    const float* x     = (const float*)d_in[0];
    const float* wgt   = (const float*)d_in[1];
    const float* gamma = (const float*)d_in[2];
    const float* beta  = (const float*)d_in[3];
    const float* mean  = (const float*)d_in[4];
    const float* var   = (const float*)d_in[5];
    float* out = (float*)d_out;

    unsigned short* wpp    = (unsigned short*)d_ws;
    unsigned short* frames = wpp + FR_U;

    if (ws_size < WS_TOTAL_BYTES) return;

    hipMemsetAsync(d_ws, 0, WS_TOTAL_BYTES, stream);
    wprep_k<<<dim3(576), 256, 0, stream>>>(wgt, wpp);
    conv_mfma_k<<<dim3(28, NBT), 256, 0, stream>>>(x, wpp, gamma, beta, mean, var, frames);
    pad_k<<<dim3(56, 6, NBC), 64, 0, stream>>>(out);
    corr_f5_k<<<dim3(56, TSEG, NBC), 320, 0, stream>>>(frames, out);
}

// Round 16
// 246.508 us; speedup vs baseline: 1.1889x; 1.1889x over previous
//
#include <hip/hip_runtime.h>
#include <hip/hip_bf16.h>

// Problem constants
#define TSEG 8
#define NBC 4          // clips
#define NBT 32         // B*T
#define CIN 256
#define CH 64
#define HIN 112
#define WIN_ 112
#define HO 56
#define WO 56
#define HPD 64
#define WPD 64

#define FRSZE ((size_t)(HPD * WPD * CH))    // 262144 bf16 elems per padded frame
#define ZF_U   147456
#define FR_U   (ZF_U + 262144)               // ushort offset of the 32 real frames
#define WS_TOTAL_BYTES ((size_t)(FR_U + 32 * 262144) * 2)   // 17,596,416 B

typedef __attribute__((ext_vector_type(8))) short bf16x8;
typedef __attribute__((ext_vector_type(4))) float f32x4;

// hardware RNE f32->bf16 (compiler fuses adjacent pairs to v_cvt_pk_bf16_f32)
__device__ __forceinline__ unsigned short f2bf(float f) {
    __hip_bfloat16 h = __float2bfloat16(f);
    union { __hip_bfloat16 h; unsigned short u; } c; c.h = h;
    return c.u;
}
__device__ __forceinline__ unsigned pk2bf(float lo, float hi) {
    return (unsigned)f2bf(lo) | ((unsigned)f2bf(hi) << 16);
}

// ---------------------------------------------------------------------------
// Weight prep: w[cout][ci][kh][kw] fp32 -> w''[tap][cout][ci] bf16 (RNE)
// ---------------------------------------------------------------------------
__global__ __launch_bounds__(256) void wprep_k(
    const float* __restrict__ w, unsigned short* __restrict__ wpp)
{
    int e = blockIdx.x * 256 + threadIdx.x;     // < 147456
    int cout = e / 2304;
    int rem  = e - cout * 2304;
    int ci   = rem / 9;
    int tap  = rem - ci * 9;
    wpp[((size_t)tap * 64 + cout) * 256 + ci] = f2bf(w[e]);
}

// ---------------------------------------------------------------------------
// Conv3x3 s2 p1 + BN + ReLU + per-pixel L2 norm, via bf16 MFMA implicit GEMM.
// R16: T14 async-STAGE split — next chunk's rows 0..1 loads issued BEFORE
// this chunk's MFMA phase (latency hides under MFMA+ds_read); converted and
// ds_written after the next barrier. Rows 2..4 staged as before (R13 float2).
// ---------------------------------------------------------------------------
__global__ __launch_bounds__(256) void conv_mfma_k(
    const float* __restrict__ x, const unsigned short* __restrict__ wpp,
    const float* __restrict__ gamma, const float* __restrict__ beta,
    const float* __restrict__ mean, const float* __restrict__ var,
    unsigned short* __restrict__ frames)
{
    __shared__ unsigned short in_lds[5 * 120 * 32];   // 38,400 B, swizzled
    __shared__ float sq[2][2][64];

    const int tid  = threadIdx.x;
    const int lane = tid & 63;
    const int wv   = tid >> 6;
    const int r    = wv >> 1;        // wave's output row within block (0/1)
    const int nh   = wv & 1;         // cout half (0/1)
    const int l15  = lane & 15;
    const int l4   = lane >> 4;      // 0..3
    const int hb   = blockIdx.x;
    const int bt   = blockIdx.y;

    const float* xb = x + (size_t)bt * (CIN * HIN * WIN_);

    f32x4 acc[4][2];
#pragma unroll
    for (int mt = 0; mt < 4; ++mt) {
        acc[mt][0] = (f32x4){0.f, 0.f, 0.f, 0.f};
        acc[mt][1] = (f32x4){0.f, 0.f, 0.f, 0.f};
    }

    int a_off[4][3];
#pragma unroll
    for (int mt = 0; mt < 4; ++mt) {
        int c = mt * 16 + l15; if (c > 55) c = 55;
#pragma unroll
        for (int kw = 0; kw < 3; ++kw) {
            int col = 2 * c + kw;
            int ba  = col * 64 + l4 * 16;
            ba ^= ((col >> 1) & 7) << 4;
            a_off[mt][kw] = ba;
        }
    }

    const unsigned short* bptr0 = wpp + ((size_t)(nh * 32 + l15) * 256 + l4 * 8);
    const unsigned short* bptr1 = wpp + ((size_t)(nh * 32 + 16 + l15) * 256 + l4 * 8);

    const int ih0 = 4 * hb - 1;

    // pre-zero the col-0 LDS slots (5 rows x 4 cigs); never written in-loop
    if (tid < 20) {
        const int row = tid >> 2, cig = tid & 3;
        const int ba = (row * 120) * 64 + cig * 16;
        *(uint4*)((char*)in_lds + ba) = make_uint4(0u, 0u, 0u, 0u);
    }

    // prefetch regs: rows 0..1 (j=0: row0/cig=wv, j=1: row1/cig=wv)
    float2 pv[2][4][2];

// issue next chunk's rows 0..1 loads (no conversion yet)
#define PFJ(cbn) \
    if (lane < 56) { \
        _Pragma("unroll") \
        for (int j = 0; j < 2; ++j) { \
            const int ih = ih0 + j; \
            if (ih >= 0 && ih < HIN) { \
                const float* xr = xb + ((size_t)((cbn) * 32 + wv * 8) * HIN + ih) * WIN_ \
                                + 2 * lane; \
                _Pragma("unroll") \
                for (int q = 0; q < 4; ++q) { \
                    pv[j][q][0] = *(const float2*)(xr + (size_t)(2 * q) * (HIN * WIN_)); \
                    pv[j][q][1] = *(const float2*)(xr + (size_t)(2 * q + 1) * (HIN * WIN_)); \
                } \
            } \
        } \
    }

// convert + ds_write the prefetched rows 0..1
#define WRJ() \
    if (lane < 56) { \
        _Pragma("unroll") \
        for (int j = 0; j < 2; ++j) { \
            const int ih = ih0 + j; \
            unsigned pkA[4], pkB[4]; \
            if (ih >= 0 && ih < HIN) { \
                _Pragma("unroll") \
                for (int q = 0; q < 4; ++q) { \
                    pkA[q] = pk2bf(pv[j][q][0].x, pv[j][q][1].x); \
                    pkB[q] = pk2bf(pv[j][q][0].y, pv[j][q][1].y); \
                } \
            } else { \
                _Pragma("unroll") \
                for (int q = 0; q < 4; ++q) { pkA[q] = 0u; pkB[q] = 0u; } \
            } \
            const int colA = 1 + 2 * lane; \
            const int colB = colA + 1; \
            int baA = (j * 120 + colA) * 64 + wv * 16; baA ^= ((colA >> 1) & 7) << 4; \
            int baB = (j * 120 + colB) * 64 + wv * 16; baB ^= ((colB >> 1) & 7) << 4; \
            *(uint4*)((char*)in_lds + baA) = make_uint4(pkA[0], pkA[1], pkA[2], pkA[3]); \
            *(uint4*)((char*)in_lds + baB) = make_uint4(pkB[0], pkB[1], pkB[2], pkB[3]); \
        } \
    }

    PFJ(0);

    for (int cb = 0; cb < 8; ++cb) {
        __syncthreads();
        // ---- write prefetched rows 0..1, stage rows 2..4 (this chunk) ----
        WRJ();
        if (lane < 56) {
#pragma unroll
            for (int j = 2; j < 5; ++j) {
                const int jj  = wv + j * 4;           // 8..19
                const int row = jj >> 2, cig = jj & 3;
                const int ih  = ih0 + row;
                unsigned pkA[4], pkB[4];
                if (ih >= 0 && ih < HIN) {
                    const float* xr = xb + ((size_t)(cb * 32 + cig * 8) * HIN + ih) * WIN_
                                    + 2 * lane;
#pragma unroll
                    for (int q = 0; q < 4; ++q) {
                        const float2 va = *(const float2*)(xr + (size_t)(2 * q) * (HIN * WIN_));
                        const float2 vb = *(const float2*)(xr + (size_t)(2 * q + 1) * (HIN * WIN_));
                        pkA[q] = pk2bf(va.x, vb.x);
                        pkB[q] = pk2bf(va.y, vb.y);
                    }
                } else {
#pragma unroll
                    for (int q = 0; q < 4; ++q) { pkA[q] = 0u; pkB[q] = 0u; }
                }
                const int colA = 1 + 2 * lane;
                const int colB = colA + 1;
                int baA = (row * 120 + colA) * 64 + cig * 16; baA ^= ((colA >> 1) & 7) << 4;
                int baB = (row * 120 + colB) * 64 + cig * 16; baB ^= ((colB >> 1) & 7) << 4;
                *(uint4*)((char*)in_lds + baA) = make_uint4(pkA[0], pkA[1], pkA[2], pkA[3]);
                *(uint4*)((char*)in_lds + baB) = make_uint4(pkB[0], pkB[1], pkB[2], pkB[3]);
            }
        }
        // issue NEXT chunk's rows 0..1 loads; latency hides under MFMA below
        if (cb < 7) { PFJ(cb + 1); }
        __syncthreads();

        // ---- 9 taps x (4 m-tiles x 2 n-tiles) MFMAs on this ci-chunk ----
        const int rowb = (2 * r) * 7680;
#pragma unroll
        for (int kh = 0; kh < 3; ++kh) {
            const int rb = rowb + kh * 7680;
#pragma unroll
            for (int kw = 0; kw < 3; ++kw) {
                const int tap = kh * 3 + kw;
                const bf16x8 bf0 = *(const bf16x8*)(bptr0 + tap * 16384 + cb * 32);
                const bf16x8 bf1 = *(const bf16x8*)(bptr1 + tap * 16384 + cb * 32);
#pragma unroll
                for (int mt = 0; mt < 4; ++mt) {
                    const bf16x8 af = *(const bf16x8*)((const char*)in_lds + (rb + a_off[mt][kw]));
                    acc[mt][0] = __builtin_amdgcn_mfma_f32_16x16x32_bf16(af, bf0, acc[mt][0], 0, 0, 0);
                    acc[mt][1] = __builtin_amdgcn_mfma_f32_16x16x32_bf16(af, bf1, acc[mt][1], 0, 0, 0);
                }
            }
        }
    }
#undef PFJ
#undef WRJ

    // ---- epilogue: BN + ReLU + cross-lane/wave L2 norm + store bf16 ----
    const int cout0 = nh * 32 + l15;
    const int cout1 = cout0 + 16;
    const float sc0 = gamma[cout0] * rsqrtf(var[cout0] + 1e-5f);
    const float bb0 = beta[cout0] - mean[cout0] * sc0;
    const float sc1 = gamma[cout1] * rsqrtf(var[cout1] + 1e-5f);
    const float bb1 = beta[cout1] - mean[cout1] * sc1;

    float yv[4][2][4];
    float ssr[4][4];
#pragma unroll
    for (int mt = 0; mt < 4; ++mt) {
#pragma unroll
        for (int reg = 0; reg < 4; ++reg) {
            float y0 = fmaxf(fmaf(acc[mt][0][reg], sc0, bb0), 0.f);
            float y1 = fmaxf(fmaf(acc[mt][1][reg], sc1, bb1), 0.f);
            yv[mt][0][reg] = y0; yv[mt][1][reg] = y1;
            float ss = y0 * y0 + y1 * y1;
            ss += __shfl_xor(ss, 1);
            ss += __shfl_xor(ss, 2);
            ss += __shfl_xor(ss, 4);
            ss += __shfl_xor(ss, 8);
            ssr[mt][reg] = ss;
        }
    }
    if (l15 == 0) {
#pragma unroll
        for (int mt = 0; mt < 4; ++mt)
#pragma unroll
            for (int reg = 0; reg < 4; ++reg)
                sq[r][nh][mt * 16 + l4 * 4 + reg] = ssr[mt][reg];
    }
    __syncthreads();

    const int h = 2 * hb + r;
    unsigned short* fdst = frames + (size_t)bt * FRSZE + (size_t)(h + 4) * WPD * CH;
#pragma unroll
    for (int mt = 0; mt < 4; ++mt) {
#pragma unroll
        for (int reg = 0; reg < 4; ++reg) {
            const int c = mt * 16 + l4 * 4 + reg;
            if (c < 56) {
                const float tot = sq[r][0][c] + sq[r][1][c];
                const float inv = rsqrtf(tot + 1e-6f);
                unsigned short* dp = fdst + (size_t)(c + 4) * CH;
                dp[cout0] = f2bf(yv[mt][0][reg] * inv);
                dp[cout1] = f2bf(yv[mt][1][reg] * inv);
            }
        }
    }
}

// ---------------------------------------------------------------------------
// Kernel 2: windowed correlation via banded Gram matrices on MFMA.
// EXACT R5 structure (best measured): one 64-thread block per (b,t,l,h),
// no barriers, 3 rotating B-buffers (prefetch distance 2), 18.8 KB slab,
// single coalesced flush. At 96.5% of achievable HBM BW for its traffic.
// ---------------------------------------------------------------------------
__global__ __launch_bounds__(64) void corr_mfma_k(
    const unsigned short* __restrict__ frames, float* __restrict__ out)
{
    __shared__ float so[56 * 84];          // 18,816 B

    const int lane = threadIdx.x;
    const int l15  = lane & 15;
    const int l4   = lane >> 4;
    const int h    = blockIdx.x;           // 0..55
    const int tl   = blockIdx.y;           // 0..39
    const int t    = tl / 5;
    const int l    = tl - 5 * t;
    const int b    = blockIdx.z;
    const int bt   = b * TSEG + t;

    float* ob = out + (size_t)(bt * HO + h) * (WO * 405) + l * 81;

    const int f = t + l;                   // padded frame index 0..11
    if (f < 2 || f > 9) {
        // temporal pad: output is exactly zero
#pragma unroll 4
        for (int w = 0; w < 56; ++w) {
            float* orow = ob + (size_t)w * 405;
            orow[lane] = 0.f;
            if (lane < 17) orow[lane + 64] = 0.f;
        }
        return;
    }

    // A fragments: Y[w][c] from padded row h+4 of center frame (w = 16m + l15)
    const unsigned short* yrow = frames + (size_t)bt * FRSZE + (size_t)(h + 4) * (WPD * CH);
    bf16x8 af[4][2];
#pragma unroll
    for (int m = 0; m < 4; ++m) {
        int w = (m << 4) + l15; if (w > 55) w = 55;  // clamp (masked at extract)
        const unsigned short* ap = yrow + (size_t)(w + 4) * CH + (l4 << 3);
        af[m][0] = *(const bf16x8*)(ap);
        af[m][1] = *(const bf16x8*)(ap + 32);
    }

    const unsigned short* zb = frames + (size_t)(b * TSEG + f - 2) * FRSZE
                             + (size_t)h * (WPD * CH);

    const int PM[7] = {0, 0, 1, 1, 2, 2, 3};
    const int PN[7] = {0, 1, 1, 2, 2, 3, 3};

#define LOADB(buf, uu) { \
    const unsigned short* zr = zb + (size_t)(uu) * (WPD * CH); \
    _Pragma("unroll") \
    for (int n = 0; n < 4; ++n) { \
        const unsigned short* bp = zr + (size_t)((n << 4) + l15) * CH + (l4 << 3); \
        buf[n][0] = *(const bf16x8*)(bp); \
        buf[n][1] = *(const bf16x8*)(bp + 32); } }

#define COMPU(buf, uu) { \
    f32x4 acc[7]; \
    _Pragma("unroll") \
    for (int i = 0; i < 7; ++i) acc[i] = (f32x4){0.f, 0.f, 0.f, 0.f}; \
    _Pragma("unroll") \
    for (int i = 0; i < 7; ++i) { \
        acc[i] = __builtin_amdgcn_mfma_f32_16x16x32_bf16(af[PM[i]][0], buf[PN[i]][0], acc[i], 0, 0, 0); \
        acc[i] = __builtin_amdgcn_mfma_f32_16x16x32_bf16(af[PM[i]][1], buf[PN[i]][1], acc[i], 0, 0, 0); } \
    _Pragma("unroll") \
    for (int i = 0; i < 7; ++i) { \
        const int zc = (PN[i] << 4) + l15; \
        const int w0 = (PM[i] << 4) + (l4 << 2); \
        _Pragma("unroll") \
        for (int rr = 0; rr < 4; ++rr) { \
            const int w = w0 + rr; \
            const int v = zc - w; \
            if (w < 56 && (unsigned)v <= 8u) \
                so[w * 84 + (uu) * 9 + v] = acc[i][rr]; } } }

    bf16x8 b0[4][2], b1[4][2], b2[4][2];
    LOADB(b0, 0); LOADB(b1, 1);
    LOADB(b2, 2); COMPU(b0, 0);
    LOADB(b0, 3); COMPU(b1, 1);
    LOADB(b1, 4); COMPU(b2, 2);
    LOADB(b2, 5); COMPU(b0, 3);
    LOADB(b0, 6); COMPU(b1, 4);
    LOADB(b1, 7); COMPU(b2, 5);
    LOADB(b2, 8); COMPU(b0, 6);
    COMPU(b1, 7);
    COMPU(b2, 8);

#undef LOADB
#undef COMPU

    // coalesced store of the dense 56x81 slab (single wave, LDS->global)
#pragma unroll 4
    for (int w = 0; w < 56; ++w) {
        const float* sr = so + w * 84;
        float* orow = ob + (size_t)w * 405;
        orow[lane] = sr[lane];
        if (lane < 17) orow[lane + 64] = sr[lane + 64];
    }
}

// ---------------------------------------------------------------------------
extern "C" void kernel_launch(void* const* d_in, const int* in_sizes, int n_in,
                              void* d_out, int out_size, void* d_ws, size_t ws_size,
                              hipStream_t stream)
{
    const float* x     = (const float*)d_in[0];
    const float* wgt   = (const float*)d_in[1];
    const float* gamma = (const float*)d_in[2];
    const float* beta  = (const float*)d_in[3];
    const float* mean  = (const float*)d_in[4];
    const float* var   = (const float*)d_in[5];
    float* out = (float*)d_out;

    unsigned short* wpp    = (unsigned short*)d_ws;
    unsigned short* frames = wpp + FR_U;

    if (ws_size < WS_TOTAL_BYTES) return;

    hipMemsetAsync(d_ws, 0, WS_TOTAL_BYTES, stream);
    wprep_k<<<dim3(576), 256, 0, stream>>>(wgt, wpp);
    conv_mfma_k<<<dim3(28, NBT), 256, 0, stream>>>(x, wpp, gamma, beta, mean, var, frames);
    corr_mfma_k<<<dim3(56, 40, NBC), 64, 0, stream>>>(frames, out);
}